// Round 2
// baseline (65.168 us; speedup 1.0000x reference)
//
#include <hip/hip_runtime.h>
#include <math.h>

#define HMAP 1024
#define WMAP 1024

__device__ __forceinline__ int clampi(int x, int hi) {
    return x < 0 ? 0 : (x > hi ? hi : x);
}

// One wave (64 lanes) per point. Cooperative 33x33 patch scan around the
// point: 17 independent global loads per lane (one latency round), then a
// 6-step shuffle min-reduce. Chebyshev guard makes it exact: any pixel
// outside the patch has d2 >= 17^2 = 289, so if both mins <= 289 they are
// the global mins. Full-map fallback (never taken at 30% density) keeps
// exactness unconditional. Mean accumulated via device-scope atomics; the
// last wave to finish writes d_out (no second dispatch).
__global__ __launch_bounds__(64)
void roadloss_scan(const float* __restrict__ hd_map,
                   const int* __restrict__ pred,
                   int n,
                   float* __restrict__ out,
                   float* __restrict__ ws) {
    const int pt   = blockIdx.x;
    const int lane = threadIdx.x;
    const int px = pred[2 * pt];      // row-center for d2 (pred[:,0] vs rows)
    const int py = pred[2 * pt + 1];  // col-center for d2 (pred[:,1] vs cols)

    // 2x2 neighbor check — reference swaps coords here (rows from pred[:,1],
    // cols from pred[:,0]) and JAX clamps OOB indices. All lanes load
    // redundantly (same cache line, broadcast); issued early to overlap
    // with the patch loads.
    const int r0c = clampi(py - 1, HMAP - 1), r1c = clampi(py, HMAP - 1);
    const int c0c = clampi(px - 1, WMAP - 1), c1c = clampi(px, WMAP - 1);
    const float n00 = hd_map[r0c * WMAP + c0c];
    const float n01 = hd_map[r0c * WMAP + c1c];
    const float n10 = hd_map[r1c * WMAP + c0c];
    const float n11 = hd_map[r1c * WMAP + c1c];

    float best_on = 1e30f, best_off = 1e30f;

    // Stage 1: 33x33 patch, lanes stride linearly (i/33, i%33 are
    // constant-divisor -> magic-mul, cheap).
    const int R = 16;
#pragma unroll
    for (int ii = 0; ii < 18; ++ii) {
        int i = lane + ii * 64;
        if (i < 33 * 33) {
            int dr = i / 33 - R;
            int dc = i % 33 - R;
            int r = px + dr, c = py + dc;
            if ((unsigned)r < (unsigned)HMAP && (unsigned)c < (unsigned)WMAP) {
                float v  = hd_map[r * WMAP + c];
                float d2 = (float)(dr * dr + dc * dc);  // exact in fp32
                if (v != 0.0f) best_on  = fminf(best_on,  d2);
                else           best_off = fminf(best_off, d2);
            }
        }
    }
#pragma unroll
    for (int s = 1; s < 64; s <<= 1) {
        best_on  = fminf(best_on,  __shfl_xor(best_on,  s, 64));
        best_off = fminf(best_off, __shfl_xor(best_off, s, 64));
    }

    // Fallback: exact full-map scan if the patch didn't certify both mins.
    const float guard = (float)((R + 1) * (R + 1));  // 289
    if (!(best_on <= guard && best_off <= guard)) {
        for (int i = lane; i < HMAP * WMAP; i += 64) {
            int r = i >> 10, c = i & (WMAP - 1);
            int dri = r - px, dci = c - py;
            float d2 = (float)(dri * dri + dci * dci);  // < 2^24, exact
            float v = hd_map[i];
            if (v != 0.0f) best_on  = fminf(best_on,  d2);
            else           best_off = fminf(best_off, d2);
        }
#pragma unroll
        for (int s = 1; s < 64; s <<= 1) {
            best_on  = fminf(best_on,  __shfl_xor(best_on,  s, 64));
            best_off = fminf(best_off, __shfl_xor(best_off, s, 64));
        }
    }

    if (lane == 0) {
        bool outside_frame = (px < 0) | (px > HMAP) | (py < 0) | (py > WMAP);
        bool outside_road  = (n00 == 1.0f) | (n01 == 1.0f) |
                             (n10 == 1.0f) | (n11 == 1.0f);
        const float K1 = 21.7f, K2 = 40.0f;
        const float LN2 = 0.6931471805599453f;
        float loss = outside_frame
                         ? 0.0f
                         : (outside_road ? expf(sqrtf(best_off) * (LN2 / K2))
                                         : expf(-best_on / K1));
        atomicAdd(&ws[0], loss);                 // device-scope sum
        __threadfence();
        unsigned old = atomicAdd((unsigned int*)(ws + 1), 1u);
        if (old == (unsigned)(n - 1)) {
            // All n sum-adds happened-before their count-adds (fence above),
            // so an atomic RMW read here sees the complete sum.
            float total = atomicAdd(&ws[0], 0.0f);
            out[0] = total / (float)n;
        }
    }
}

extern "C" void kernel_launch(void* const* d_in, const int* in_sizes, int n_in,
                              void* d_out, int out_size, void* d_ws, size_t ws_size,
                              hipStream_t stream) {
    const float* hd_map = (const float*)d_in[0];
    const int*   pred   = (const int*)d_in[1];
    float* out = (float*)d_out;
    float* ws  = (float*)d_ws;
    int n = in_sizes[1] / 2;  // 128

    // Zero the accumulator {float sum, uint count} — d_ws is poisoned 0xAA
    // before every replay. hipMemsetAsync is graph-capture legal.
    hipMemsetAsync(ws, 0, 2 * sizeof(float), stream);
    roadloss_scan<<<n, 64, 0, stream>>>(hd_map, pred, n, out, ws);
}